// Round 1
// baseline (1239.971 us; speedup 1.0000x reference)
//
#include <hip/hip_runtime.h>
#include <math.h>

// Problem constants
#define BATCH 8
#define CH 256
#define HH 45
#define WW 80
#define HW 3600        // 45*80
#define PTOT 28800     // BATCH*HW
#define NPOS 32        // positions per deform block

// ---------------------------------------------------------------------------
// K1: 1x1 conv as GEMM: out1[b,o,hw] = sum_c x[b,c,hw] * w1[o,c]
// tile 64 hw x 64 oc, 256 threads, 4x4 microtile, K-chunks of 16
// ---------------------------------------------------------------------------
__global__ __launch_bounds__(256) void conv1_gemm(
    const float* __restrict__ x, const float* __restrict__ w1,
    float* __restrict__ out1)
{
  __shared__ float xs[16][68];
  __shared__ float wsm[16][68];
  const int b   = blockIdx.z;
  const int hw0 = blockIdx.x * 64;
  const int oc0 = blockIdx.y * 64;
  const int t   = threadIdx.x;
  const int tx  = t & 15;        // hw quad
  const int ty  = t >> 4;        // oc quad
  const int rem = HW - hw0;      // valid cols in this tile (>=16, mult of 16)

  float acc[4][4];
#pragma unroll
  for (int j = 0; j < 4; j++)
#pragma unroll
    for (int i = 0; i < 4; i++) acc[j][i] = 0.f;

  const float* xb = x + (size_t)b * CH * HW;

  for (int c0 = 0; c0 < CH; c0 += 16) {
    {
      int c = t >> 4, col = (t & 15) * 4;
      float4 v = make_float4(0.f, 0.f, 0.f, 0.f);
      if (col < rem) v = *(const float4*)(xb + (size_t)(c0 + c) * HW + hw0 + col);
      *(float4*)&xs[c][col] = v;
    }
    {
      int oc = t >> 2, cq = (t & 3) * 4;
      float4 wv = *(const float4*)(w1 + (size_t)(oc0 + oc) * CH + c0 + cq);
      wsm[cq + 0][oc] = wv.x;
      wsm[cq + 1][oc] = wv.y;
      wsm[cq + 2][oc] = wv.z;
      wsm[cq + 3][oc] = wv.w;
    }
    __syncthreads();
#pragma unroll
    for (int kk = 0; kk < 16; kk++) {
      float4 a  = *(const float4*)&xs[kk][tx * 4];
      float4 bb = *(const float4*)&wsm[kk][ty * 4];
      float av[4] = {a.x, a.y, a.z, a.w};
      float bv[4] = {bb.x, bb.y, bb.z, bb.w};
#pragma unroll
      for (int j = 0; j < 4; j++)
#pragma unroll
        for (int i = 0; i < 4; i++)
          acc[j][i] = fmaf(bv[j], av[i], acc[j][i]);
    }
    __syncthreads();
  }

  int col = tx * 4;
  if (col < rem) {
#pragma unroll
    for (int j = 0; j < 4; j++) {
      int oc = oc0 + ty * 4 + j;
      float4 v = make_float4(acc[j][0], acc[j][1], acc[j][2], acc[j][3]);
      *(float4*)(out1 + ((size_t)b * CH + oc) * HW + hw0 + col) = v;
    }
  }
}

// ---------------------------------------------------------------------------
// K2: per-channel mean/rstd of out1 (deterministic, one block per channel)
// st[c] = mean, st[256+c] = rstd
// ---------------------------------------------------------------------------
__global__ __launch_bounds__(256) void stats1_k(
    const float* __restrict__ out1, float* __restrict__ st)
{
  const int c = blockIdx.x;
  const int t = threadIdx.x;
  float s = 0.f, s2 = 0.f;
  for (int b = 0; b < BATCH; b++) {
    const float* p = out1 + ((size_t)b * CH + c) * HW;
    for (int i = t; i < HW; i += 256) {
      float v = p[i];
      s += v; s2 += v * v;
    }
  }
  __shared__ float ls[256], ls2[256];
  ls[t] = s; ls2[t] = s2;
  __syncthreads();
  for (int off = 128; off > 0; off >>= 1) {
    if (t < off) { ls[t] += ls[t + off]; ls2[t] += ls2[t + off]; }
    __syncthreads();
  }
  if (t == 0) {
    float m = ls[0] / (float)PTOT;
    float var = ls2[0] / (float)PTOT - m * m;
    st[c] = m;
    st[CH + c] = rsqrtf(var + 1e-5f);
  }
}

// ---------------------------------------------------------------------------
// K3: normalize out1 in place (-> xp NCHW) and write transposed xp_t NHWC.
// tile: 32 channels x 32 positions per block
// ---------------------------------------------------------------------------
__global__ __launch_bounds__(256) void norm_transpose(
    float* __restrict__ out1, const float* __restrict__ st,
    const float* __restrict__ g, const float* __restrict__ bb,
    float* __restrict__ xp_t)
{
  __shared__ float tile[32][36];   // [c][p]
  const int b  = blockIdx.z;
  const int c0 = blockIdx.y * 32;
  const int p0 = blockIdx.x * 32;
  int rem = HW - p0; if (rem > 32) rem = 32;
  const int t = threadIdx.x;

  {
    int c  = t >> 3;
    int p4 = (t & 7) * 4;
    int cg = c0 + c;
    float m  = st[cg], rs = st[CH + cg];
    float sc = g[cg] * rs;
    float sh = bb[cg] - m * sc;
    if (p4 < rem) {
      size_t base = ((size_t)b * CH + cg) * HW + p0;
      float4 v = *(const float4*)(out1 + base + p4);
      v.x = v.x * sc + sh; v.y = v.y * sc + sh;
      v.z = v.z * sc + sh; v.w = v.w * sc + sh;
      *(float4*)(out1 + base + p4) = v;
      *(float4*)&tile[c][p4] = v;
    }
  }
  __syncthreads();
  {
    int r  = t >> 3;          // position row
    int cq = (t & 7) * 4;     // channel quad
    if (r < rem) {
      float4 o;
      o.x = tile[cq + 0][r];
      o.y = tile[cq + 1][r];
      o.z = tile[cq + 2][r];
      o.w = tile[cq + 3][r];
      *(float4*)(xp_t + ((size_t)b * HW + p0 + r) * CH + c0 + cq) = o;
    }
  }
}

// ---------------------------------------------------------------------------
// K4: transpose weights.
//   wt_dcn[(k*256+c)*256+o] = dcn_w[(o*256+c)*9+k]
//   wt_off[(ic*9+kk)*27+oc] = off_w[((oc*512)+ic)*9+kk]
// ---------------------------------------------------------------------------
__global__ __launch_bounds__(256) void transpose_wts(
    const float* __restrict__ dcn_w, const float* __restrict__ off_w,
    float* __restrict__ wt_dcn, float* __restrict__ wt_off)
{
  int i = blockIdx.x * 256 + threadIdx.x;
  if (i < 256 * 256 * 9) {
    int k = i % 9;
    int c = (i / 9) % 256;
    int o = i / (9 * 256);
    wt_dcn[((size_t)k * 256 + c) * 256 + o] = dcn_w[i];
  }
  if (i < 27 * 512 * 9) {
    int kk = i % 9;
    int ic = (i / 9) % 512;
    int oc = i / (9 * 512);
    wt_off[((size_t)ic * 9 + kk) * 27 + oc] = off_w[i];
  }
}

// ---------------------------------------------------------------------------
// K5: offset conv (3x3, 512 ic -> 27 oc) over concat(flip(x), xp).
// Partial over an ic-group of 64; 8 groups -> offparts[g].
// Weight indices are wave-uniform -> scalar loads.
// ---------------------------------------------------------------------------
__global__ __launch_bounds__(256) void off_conv(
    const float* __restrict__ x, const float* __restrict__ xp,
    const float* __restrict__ wt_off, float* __restrict__ offparts)
{
  const int b = blockIdx.y;
  const int g = blockIdx.z;               // 8 groups of 64 ic
  const int p = blockIdx.x * 256 + threadIdx.x;
  const bool valid = p < HW;
  const int h = p / WW;
  const int w = p - h * WW;

  float acc[27];
#pragma unroll
  for (int i = 0; i < 27; i++) acc[i] = 0.f;

  const int ic0 = g * 64;
#pragma unroll 1
  for (int icl = 0; icl < 64; icl++) {
    int ic = ic0 + icl;
    const float* src;
    int flip;
    if (ic < 256) { src = x  + ((size_t)b * CH + ic)       * HW; flip = 1; }
    else          { src = xp + ((size_t)b * CH + ic - 256) * HW; flip = 0; }
    float v[9];
#pragma unroll
    for (int dy = -1; dy <= 1; dy++) {
      int hh = h + dy;
      bool hv = (hh >= 0) && (hh < HH);
#pragma unroll
      for (int dx = -1; dx <= 1; dx++) {
        int wc = flip ? (WW - 1 - w - dx) : (w + dx);
        bool wv = (wc >= 0) && (wc < WW);
        v[(dy + 1) * 3 + (dx + 1)] =
            (valid && hv && wv) ? src[hh * WW + wc] : 0.f;
      }
    }
    const float* wp = wt_off + (size_t)ic * 9 * 27;
#pragma unroll
    for (int tap = 0; tap < 9; tap++) {
      float vv = v[tap];
#pragma unroll
      for (int oc = 0; oc < 27; oc++)
        acc[oc] = fmaf(vv, wp[tap * 27 + oc], acc[oc]);
    }
  }
  if (valid) {
#pragma unroll
    for (int oc = 0; oc < 27; oc++)
      offparts[(((size_t)g * BATCH + b) * 27 + oc) * HW + p] = acc[oc];
  }
}

// ---------------------------------------------------------------------------
// K6: deformable conv. Block = 32 positions (one b). Output d_t in NHWC.
// ---------------------------------------------------------------------------
__global__ __launch_bounds__(256) void deform_k(
    const float* __restrict__ xp_t, const float* __restrict__ offparts,
    const float* __restrict__ off_b, const float* __restrict__ wt_dcn,
    const float* __restrict__ dcn_b, float* __restrict__ d_t)
{
  __shared__ float samp[256 * 36];        // [c][pos], pad 36
  __shared__ float wl[32][256];           // [c_local][oc]
  __shared__ int   shi[2][NPOS][9];
  __shared__ int   swi[2][NPOS][9];
  __shared__ float sW[4][NPOS][9];

  const int b  = blockIdx.y;
  const int p0 = blockIdx.x * NPOS;
  const int t  = threadIdx.x;

  // Phase A: bilinear params per (pos, k)
  for (int item = t; item < NPOS * 9; item += 256) {
    int pos = item / 9, k = item % 9;
    int p = p0 + pos;
    int pp = (p < HW) ? p : 0;
    float dy = off_b[2 * k], dx = off_b[2 * k + 1], ml = off_b[18 + k];
#pragma unroll
    for (int g2 = 0; g2 < 8; g2++) {
      const float* op = offparts + ((size_t)(g2 * BATCH + b) * 27) * HW;
      dy += op[(size_t)(2 * k    ) * HW + pp];
      dx += op[(size_t)(2 * k + 1) * HW + pp];
      ml += op[(size_t)(18 + k   ) * HW + pp];
    }
    float m = 1.f / (1.f + expf(-ml));
    int hh = pp / WW, ww2 = pp - (pp / WW) * WW;
    float ph = dy + (float)(k / 3 - 1) + (float)hh;
    float pw = dx + (float)(k % 3 - 1) + (float)ww2;
    float h0f = floorf(ph), w0f = floorf(pw);
    float lh = ph - h0f, lw = pw - w0f;
    int h0 = (int)h0f, w0 = (int)w0f;
    int h1 = h0 + 1, w1 = w0 + 1;
    float vh0 = (h0 >= 0 && h0 < HH) ? 1.f : 0.f;
    float vh1 = (h1 >= 0 && h1 < HH) ? 1.f : 0.f;
    float vw0 = (w0 >= 0 && w0 < WW) ? 1.f : 0.f;
    float vw1 = (w1 >= 0 && w1 < WW) ? 1.f : 0.f;
    sW[0][pos][k] = (1.f - lh) * (1.f - lw) * m * vh0 * vw0;
    sW[1][pos][k] = (1.f - lh) * lw         * m * vh0 * vw1;
    sW[2][pos][k] = lh * (1.f - lw)         * m * vh1 * vw0;
    sW[3][pos][k] = lh * lw                 * m * vh1 * vw1;
    shi[0][pos][k] = min(max(h0, 0), HH - 1);
    shi[1][pos][k] = min(max(h1, 0), HH - 1);
    swi[0][pos][k] = min(max(w0, 0), WW - 1);
    swi[1][pos][k] = min(max(w1, 0), WW - 1);
  }

  float acc[4][8];
#pragma unroll
  for (int j = 0; j < 4; j++)
#pragma unroll
    for (int o = 0; o < 8; o++) acc[j][o] = 0.f;

  const float* xb = xp_t + (size_t)b * HW * CH;
  const int ocb  = (t & 31) * 8;
  const int posb = (t >> 5) * 4;

  for (int k = 0; k < 9; k++) {
    __syncthreads();   // params ready / prev GEMM done with samp
    // build samp: this thread handles channel c = t for all 32 positions
#pragma unroll 4
    for (int pos = 0; pos < NPOS; pos++) {
      int h0 = shi[0][pos][k], h1 = shi[1][pos][k];
      int w0 = swi[0][pos][k], w1 = swi[1][pos][k];
      float w00 = sW[0][pos][k], w01 = sW[1][pos][k];
      float w10 = sW[2][pos][k], w11 = sW[3][pos][k];
      float v00 = xb[(size_t)(h0 * WW + w0) * CH + t];
      float v01 = xb[(size_t)(h0 * WW + w1) * CH + t];
      float v10 = xb[(size_t)(h1 * WW + w0) * CH + t];
      float v11 = xb[(size_t)(h1 * WW + w1) * CH + t];
      samp[t * 36 + pos] = w00 * v00 + w01 * v01 + w10 * v10 + w11 * v11;
    }
    for (int cc = 0; cc < 8; cc++) {
      __syncthreads(); // samp ready (cc==0) / prev GEMM done with wl
#pragma unroll
      for (int i = 0; i < 8; i++) {
        int idx = i * 1024 + t * 4;
        int cl = idx >> 8, col = idx & 255;
        *(float4*)&wl[cl][col] =
            *(const float4*)(wt_dcn + ((size_t)(k * 256) + cc * 32 + cl) * 256 + col);
      }
      __syncthreads();
#pragma unroll
      for (int cl = 0; cl < 32; cl++) {
        float4 s4 = *(const float4*)&samp[(cc * 32 + cl) * 36 + posb];
        float sv[4] = {s4.x, s4.y, s4.z, s4.w};
        float4 wq0 = *(const float4*)&wl[cl][ocb];
        float4 wq1 = *(const float4*)&wl[cl][ocb + 4];
        float wv[8] = {wq0.x, wq0.y, wq0.z, wq0.w, wq1.x, wq1.y, wq1.z, wq1.w};
#pragma unroll
        for (int o = 0; o < 8; o++) {
#pragma unroll
          for (int j = 0; j < 4; j++)
            acc[j][o] = fmaf(sv[j], wv[o], acc[j][o]);
        }
      }
    }
  }

#pragma unroll
  for (int j = 0; j < 4; j++) {
    int p = p0 + posb + j;
    if (p < HW) {
      float ov[8];
#pragma unroll
      for (int o = 0; o < 8; o++) ov[o] = acc[j][o] + dcn_b[ocb + o];
      float* dst = d_t + ((size_t)b * HW + p) * CH + ocb;
      *(float4*)dst       = make_float4(ov[0], ov[1], ov[2], ov[3]);
      *(float4*)(dst + 4) = make_float4(ov[4], ov[5], ov[6], ov[7]);
    }
  }
}

// ---------------------------------------------------------------------------
// K7/K8: stats of d_t (NHWC) -> scale/shift with norm_g/norm_b folded
// ---------------------------------------------------------------------------
__global__ __launch_bounds__(256) void stats2_k(
    const float* __restrict__ d_t, float* __restrict__ part)
{
  const int t = threadIdx.x;
  const int bl = blockIdx.x;   // 256 blocks
  float s = 0.f, s2 = 0.f;
  for (int P = bl; P < PTOT; P += 256) {
    float v = d_t[(size_t)P * CH + t];
    s += v; s2 += v * v;
  }
  part[(size_t)bl * 512 + t] = s;
  part[(size_t)bl * 512 + 256 + t] = s2;
}

__global__ __launch_bounds__(256) void stats2b_k(
    const float* __restrict__ part, const float* __restrict__ norm_g,
    const float* __restrict__ norm_b, float* __restrict__ st2)
{
  const int t = threadIdx.x;
  float s = 0.f, s2 = 0.f;
  for (int bl = 0; bl < 256; bl++) {
    s  += part[(size_t)bl * 512 + t];
    s2 += part[(size_t)bl * 512 + 256 + t];
  }
  float m = s / (float)PTOT;
  float var = s2 / (float)PTOT - m * m;
  float rs = rsqrtf(var + 1e-5f);
  float sc = norm_g[t] * rs;
  st2[t] = sc;
  st2[CH + t] = norm_b[t] - m * sc;
}

// ---------------------------------------------------------------------------
// K9: final = relu(d*scale + shift + xp), NHWC reads -> NCHW write via LDS
// ---------------------------------------------------------------------------
__global__ __launch_bounds__(256) void final_k(
    const float* __restrict__ d_t, const float* __restrict__ xp_t,
    const float* __restrict__ st2, float* __restrict__ out)
{
  __shared__ float tile[32][260];   // [p_local][c]
  const int P0 = blockIdx.x * 32;
  const int t  = threadIdx.x;
  float sc = st2[t], sh = st2[CH + t];
#pragma unroll 4
  for (int r = 0; r < 32; r++) {
    size_t idx = (size_t)(P0 + r) * CH + t;
    float v = d_t[idx] * sc + sh + xp_t[idx];
    tile[r][t] = v > 0.f ? v : 0.f;
  }
  __syncthreads();
  const int tq = t & 7;         // p quad
  const int rr = t >> 3;        // 0..31
#pragma unroll
  for (int pass = 0; pass < 8; pass++) {
    int c = pass * 32 + rr;
    int pi = 4 * tq;
    int P = P0 + pi;
    int b = P / HW;
    int p = P - b * HW;
    float4 v;
    v.x = tile[pi + 0][c];
    v.y = tile[pi + 1][c];
    v.z = tile[pi + 2][c];
    v.w = tile[pi + 3][c];
    *(float4*)(out + ((size_t)b * CH + c) * HW + p) = v;
  }
}

// ---------------------------------------------------------------------------
extern "C" void kernel_launch(void* const* d_in, const int* in_sizes, int n_in,
                              void* d_out, int out_size, void* d_ws, size_t ws_size,
                              hipStream_t stream)
{
  const float* x       = (const float*)d_in[0];
  const float* conv1_w = (const float*)d_in[1];
  const float* bn1_g   = (const float*)d_in[2];
  const float* bn1_b   = (const float*)d_in[3];
  const float* off_w   = (const float*)d_in[4];
  const float* off_b   = (const float*)d_in[5];
  const float* dcn_w   = (const float*)d_in[6];
  const float* dcn_b   = (const float*)d_in[7];
  const float* norm_g  = (const float*)d_in[8];
  const float* norm_b  = (const float*)d_in[9];
  float* out = (float*)d_out;

  char* ws = (char*)d_ws;
  size_t o = 0;
  float* out1   = (float*)(ws + o); o += (size_t)PTOT * CH * 4;        // 29.5 MB (becomes xp NCHW)
  float* xp_t   = (float*)(ws + o); o += (size_t)PTOT * CH * 4;        // 29.5 MB NHWC
  float* offp   = (float*)(ws + o); o += (size_t)8 * BATCH * 27 * HW * 4; // 24.9 MB
  float* d_t    = (float*)(ws + o); o += (size_t)PTOT * CH * 4;        // 29.5 MB NHWC
  float* wt_dcn = (float*)(ws + o); o += (size_t)9 * 256 * 256 * 4;    // 2.36 MB
  float* wt_off = (float*)(ws + o); o += (size_t)512 * 9 * 27 * 4;     // 0.5 MB
  float* st     = (float*)(ws + o); o += 512 * 4;
  float* part   = (float*)(ws + o); o += (size_t)256 * 512 * 4;
  float* st2    = (float*)(ws + o); o += 512 * 4;

  conv1_gemm<<<dim3(57, 4, 8), 256, 0, stream>>>(x, conv1_w, out1);
  stats1_k<<<256, 256, 0, stream>>>(out1, st);
  norm_transpose<<<dim3(113, 8, 8), 256, 0, stream>>>(out1, st, bn1_g, bn1_b, xp_t);
  transpose_wts<<<2304, 256, 0, stream>>>(dcn_w, off_w, wt_dcn, wt_off);
  off_conv<<<dim3(15, 8, 8), 256, 0, stream>>>(x, out1, wt_off, offp);
  deform_k<<<dim3(113, 8), 256, 0, stream>>>(xp_t, offp, off_b, wt_dcn, dcn_b, d_t);
  stats2_k<<<256, 256, 0, stream>>>(d_t, part);
  stats2b_k<<<1, 256, 0, stream>>>(part, norm_g, norm_b, st2);
  final_k<<<900, 256, 0, stream>>>(d_t, xp_t, st2, out);
}

// Round 2
// 510.018 us; speedup vs baseline: 2.4312x; 2.4312x over previous
//
#include <hip/hip_runtime.h>
#include <math.h>

// Problem constants
#define BATCH 8
#define CH 256
#define HH 45
#define WW 80
#define HW 3600        // 45*80
#define PTOT 28800     // BATCH*HW

typedef unsigned short u16;
typedef unsigned int   u32;
typedef __attribute__((ext_vector_type(8))) short bf16x8;
typedef __attribute__((ext_vector_type(4))) float f32x4;

struct __align__(8) us4 { u16 x, y, z, w; };

__device__ __forceinline__ u16 bf16_rne(float x) {
  u32 u = __float_as_uint(x);
  u += 0x7FFF + ((u >> 16) & 1);
  return (u16)(u >> 16);
}

// ---------------------------------------------------------------------------
// K1: 1x1 conv as GEMM: out1[b,o,hw] = sum_c x[b,c,hw] * w1[o,c]
// ---------------------------------------------------------------------------
__global__ __launch_bounds__(256) void conv1_gemm(
    const float* __restrict__ x, const float* __restrict__ w1,
    float* __restrict__ out1)
{
  __shared__ float xs[16][68];
  __shared__ float wsm[16][68];
  const int b   = blockIdx.z;
  const int hw0 = blockIdx.x * 64;
  const int oc0 = blockIdx.y * 64;
  const int t   = threadIdx.x;
  const int tx  = t & 15;
  const int ty  = t >> 4;
  const int rem = HW - hw0;

  float acc[4][4];
#pragma unroll
  for (int j = 0; j < 4; j++)
#pragma unroll
    for (int i = 0; i < 4; i++) acc[j][i] = 0.f;

  const float* xb = x + (size_t)b * CH * HW;

  for (int c0 = 0; c0 < CH; c0 += 16) {
    {
      int c = t >> 4, col = (t & 15) * 4;
      float4 v = make_float4(0.f, 0.f, 0.f, 0.f);
      if (col < rem) v = *(const float4*)(xb + (size_t)(c0 + c) * HW + hw0 + col);
      *(float4*)&xs[c][col] = v;
    }
    {
      int oc = t >> 2, cq = (t & 3) * 4;
      float4 wv = *(const float4*)(w1 + (size_t)(oc0 + oc) * CH + c0 + cq);
      wsm[cq + 0][oc] = wv.x;
      wsm[cq + 1][oc] = wv.y;
      wsm[cq + 2][oc] = wv.z;
      wsm[cq + 3][oc] = wv.w;
    }
    __syncthreads();
#pragma unroll
    for (int kk = 0; kk < 16; kk++) {
      float4 a  = *(const float4*)&xs[kk][tx * 4];
      float4 bb = *(const float4*)&wsm[kk][ty * 4];
      float av[4] = {a.x, a.y, a.z, a.w};
      float bv[4] = {bb.x, bb.y, bb.z, bb.w};
#pragma unroll
      for (int j = 0; j < 4; j++)
#pragma unroll
        for (int i = 0; i < 4; i++)
          acc[j][i] = fmaf(bv[j], av[i], acc[j][i]);
    }
    __syncthreads();
  }

  int col = tx * 4;
  if (col < rem) {
#pragma unroll
    for (int j = 0; j < 4; j++) {
      int oc = oc0 + ty * 4 + j;
      float4 v = make_float4(acc[j][0], acc[j][1], acc[j][2], acc[j][3]);
      *(float4*)(out1 + ((size_t)b * CH + oc) * HW + hw0 + col) = v;
    }
  }
}

// ---------------------------------------------------------------------------
// K2: per-channel mean/rstd over NCHW (used for out1 and for d)
// st[c] = mean, st[256+c] = rstd
// ---------------------------------------------------------------------------
__global__ __launch_bounds__(256) void stats_nchw(
    const float* __restrict__ src, float* __restrict__ st)
{
  const int c = blockIdx.x;
  const int t = threadIdx.x;
  float s = 0.f, s2 = 0.f;
  for (int b = 0; b < BATCH; b++) {
    const float* p = src + ((size_t)b * CH + c) * HW;
    for (int i = t; i < HW; i += 256) {
      float v = p[i];
      s += v; s2 += v * v;
    }
  }
  __shared__ float ls[256], ls2[256];
  ls[t] = s; ls2[t] = s2;
  __syncthreads();
  for (int off = 128; off > 0; off >>= 1) {
    if (t < off) { ls[t] += ls[t + off]; ls2[t] += ls2[t + off]; }
    __syncthreads();
  }
  if (t == 0) {
    float m = ls[0] / (float)PTOT;
    float var = ls2[0] / (float)PTOT - m * m;
    st[c] = m;
    st[CH + c] = rsqrtf(var + 1e-5f);
  }
}

// ---------------------------------------------------------------------------
// K3: normalize out1 in place (-> xp NCHW f32) and write xp_tb NHWC bf16
// ---------------------------------------------------------------------------
__global__ __launch_bounds__(256) void norm_transpose(
    float* __restrict__ out1, const float* __restrict__ st,
    const float* __restrict__ g, const float* __restrict__ bb,
    u16* __restrict__ xp_tb)
{
  __shared__ float tile[32][36];   // [c][p]
  const int b  = blockIdx.z;
  const int c0 = blockIdx.y * 32;
  const int p0 = blockIdx.x * 32;
  int rem = HW - p0; if (rem > 32) rem = 32;
  const int t = threadIdx.x;

  {
    int c  = t >> 3;
    int p4 = (t & 7) * 4;
    int cg = c0 + c;
    float m  = st[cg], rs = st[CH + cg];
    float sc = g[cg] * rs;
    float sh = bb[cg] - m * sc;
    if (p4 < rem) {
      size_t base = ((size_t)b * CH + cg) * HW + p0;
      float4 v = *(const float4*)(out1 + base + p4);
      v.x = v.x * sc + sh; v.y = v.y * sc + sh;
      v.z = v.z * sc + sh; v.w = v.w * sc + sh;
      *(float4*)(out1 + base + p4) = v;
      *(float4*)&tile[c][p4] = v;
    }
  }
  __syncthreads();
  {
    int r  = t >> 3;          // position row
    int cq = (t & 7) * 4;     // channel quad
    if (r < rem) {
      us4 o;
      o.x = bf16_rne(tile[cq + 0][r]);
      o.y = bf16_rne(tile[cq + 1][r]);
      o.z = bf16_rne(tile[cq + 2][r]);
      o.w = bf16_rne(tile[cq + 3][r]);
      *(us4*)(xp_tb + ((size_t)b * HW + p0 + r) * CH + c0 + cq) = o;
    }
  }
}

// ---------------------------------------------------------------------------
// K4: weight prep.
//   wt_b[tap][oc][c] (bf16)  = dcn_w[oc][c][tap]
//   wt_off[(ic*9+kk)*27+oc]  = off_w[((oc*512)+ic)*9+kk]   (f32)
// ---------------------------------------------------------------------------
__global__ __launch_bounds__(256) void prep_wts(
    const float* __restrict__ dcn_w, const float* __restrict__ off_w,
    u16* __restrict__ wt_b, float* __restrict__ wt_off)
{
  int i = blockIdx.x * 256 + threadIdx.x;
  if (i < 9 * 256 * 256) {
    int c = i & 255;
    int oc = (i >> 8) & 255;
    int tap = i >> 16;
    float v = dcn_w[((size_t)oc * 256 + c) * 9 + tap];
    wt_b[i] = bf16_rne(v);
  }
  if (i < 27 * 512 * 9) {
    int kk = i % 9;
    int ic = (i / 9) % 512;
    int oc = i / (9 * 512);
    wt_off[((size_t)ic * 9 + kk) * 27 + oc] = off_w[i];
  }
}

// ---------------------------------------------------------------------------
// K5: offset conv (3x3, 512 ic -> 27 oc) over concat(flip(x), xp).
// ---------------------------------------------------------------------------
__global__ __launch_bounds__(256) void off_conv(
    const float* __restrict__ x, const float* __restrict__ xp,
    const float* __restrict__ wt_off, float* __restrict__ offparts)
{
  const int b = blockIdx.y;
  const int g = blockIdx.z;
  const int p = blockIdx.x * 256 + threadIdx.x;
  const bool valid = p < HW;
  const int h = p / WW;
  const int w = p - h * WW;

  float acc[27];
#pragma unroll
  for (int i = 0; i < 27; i++) acc[i] = 0.f;

  const int ic0 = g * 64;
#pragma unroll 1
  for (int icl = 0; icl < 64; icl++) {
    int ic = ic0 + icl;
    const float* src;
    int flip;
    if (ic < 256) { src = x  + ((size_t)b * CH + ic)       * HW; flip = 1; }
    else          { src = xp + ((size_t)b * CH + ic - 256) * HW; flip = 0; }
    float v[9];
#pragma unroll
    for (int dy = -1; dy <= 1; dy++) {
      int hh = h + dy;
      bool hv = (hh >= 0) && (hh < HH);
#pragma unroll
      for (int dx = -1; dx <= 1; dx++) {
        int wc = flip ? (WW - 1 - w - dx) : (w + dx);
        bool wv = (wc >= 0) && (wc < WW);
        v[(dy + 1) * 3 + (dx + 1)] =
            (valid && hv && wv) ? src[hh * WW + wc] : 0.f;
      }
    }
    const float* wp = wt_off + (size_t)ic * 9 * 27;
#pragma unroll
    for (int tap = 0; tap < 9; tap++) {
      float vv = v[tap];
#pragma unroll
      for (int oc = 0; oc < 27; oc++)
        acc[oc] = fmaf(vv, wp[tap * 27 + oc], acc[oc]);
    }
  }
  if (valid) {
#pragma unroll
    for (int oc = 0; oc < 27; oc++)
      offparts[(((size_t)g * BATCH + b) * 27 + oc) * HW + p] = acc[oc];
  }
}

// ---------------------------------------------------------------------------
// K6: finalize offsets -> bilinear params per (tap, P).
//   wts4[k*PTOT+P] = 4 corner weights (incl. mask & validity)
//   idx4[k*PTOT+P] = 4 clamped element offsets into xp_tb (NHWC base)
// ---------------------------------------------------------------------------
__global__ __launch_bounds__(256) void off_finalize(
    const float* __restrict__ offparts, const float* __restrict__ off_b,
    float4* __restrict__ wts4, int4* __restrict__ idx4)
{
  int i = blockIdx.x * 256 + threadIdx.x;
  if (i >= 9 * PTOT) return;
  int k = i / PTOT;
  int P = i - k * PTOT;
  int b = P / HW;
  int p = P - b * HW;
  int h = p / WW;
  int w = p - h * WW;

  float dy = off_b[2 * k], dx = off_b[2 * k + 1], ml = off_b[18 + k];
#pragma unroll
  for (int g = 0; g < 8; g++) {
    const float* op = offparts + ((size_t)(g * BATCH + b) * 27) * HW + p;
    dy += op[(size_t)(2 * k    ) * HW];
    dx += op[(size_t)(2 * k + 1) * HW];
    ml += op[(size_t)(18 + k   ) * HW];
  }
  float m = 1.f / (1.f + expf(-ml));
  float ph = dy + (float)(k / 3 - 1) + (float)h;
  float pw = dx + (float)(k % 3 - 1) + (float)w;
  float h0f = floorf(ph), w0f = floorf(pw);
  float lh = ph - h0f, lw = pw - w0f;
  int h0 = (int)h0f, w0 = (int)w0f;
  int h1 = h0 + 1, w1 = w0 + 1;
  float vh0 = (h0 >= 0 && h0 < HH) ? 1.f : 0.f;
  float vh1 = (h1 >= 0 && h1 < HH) ? 1.f : 0.f;
  float vw0 = (w0 >= 0 && w0 < WW) ? 1.f : 0.f;
  float vw1 = (w1 >= 0 && w1 < WW) ? 1.f : 0.f;
  float4 wv;
  wv.x = (1.f - lh) * (1.f - lw) * m * vh0 * vw0;
  wv.y = (1.f - lh) * lw         * m * vh0 * vw1;
  wv.z = lh * (1.f - lw)         * m * vh1 * vw0;
  wv.w = lh * lw                 * m * vh1 * vw1;
  int hc0 = min(max(h0, 0), HH - 1), hc1 = min(max(h1, 0), HH - 1);
  int wc0 = min(max(w0, 0), WW - 1), wc1 = min(max(w1, 0), WW - 1);
  int base = b * HW;
  int4 iv;
  iv.x = (base + hc0 * WW + wc0) * CH;
  iv.y = (base + hc0 * WW + wc1) * CH;
  iv.z = (base + hc1 * WW + wc0) * CH;
  iv.w = (base + hc1 * WW + wc1) * CH;
  wts4[i] = wv;
  idx4[i] = iv;
}

// ---------------------------------------------------------------------------
// K7: deformable conv via MFMA bf16.
// Block = 128 threads (2 waves), 64 positions, all 256 oc (wave w owns 128 oc).
// Per tap: build samp[64 pos][256 c] bf16 in LDS (XOR-swizzled), then
// GEMM: A = weights [oc][c] (global bf16), B = samp, D[oc][pos] f32.
// d output NCHW f32 (no bias: it cancels in the following batchnorm).
// ---------------------------------------------------------------------------
__global__ __launch_bounds__(128) void deform_mfma(
    const u16* __restrict__ xp_tb,
    const float4* __restrict__ wts4, const int4* __restrict__ idx4,
    const u16* __restrict__ wt_b,
    float* __restrict__ d)
{
  __shared__ u16   samp[64 * 256];   // swizzled: byte ^= (pos&7)<<4
  __shared__ float4 sw4[64];
  __shared__ int4   sidx4[64];

  const int t    = threadIdx.x;
  const int wv   = t >> 6;           // wave id (0,1)
  const int lane = t & 63;
  const int P0   = blockIdx.x * 64;

  f32x4 acc[8][4];
#pragma unroll
  for (int mt = 0; mt < 8; mt++)
#pragma unroll
    for (int nt = 0; nt < 4; nt++) acc[mt][nt] = (f32x4)0.f;

  const int c4 = lane * 4;           // this lane's channel quad in build phase

  for (int tap = 0; tap < 9; tap++) {
    __syncthreads();   // previous GEMM / param reads done
    if (t < 64) {
      sw4[t]   = wts4[(size_t)tap * PTOT + P0 + t];
      sidx4[t] = idx4[(size_t)tap * PTOT + P0 + t];
    }
    __syncthreads();

    // build samp: 32 iters, each wave does one pos per iter
#pragma unroll 2
    for (int it = 0; it < 32; it++) {
      int pos = it * 2 + wv;
      int4  iv = sidx4[pos];
      float4 wq = sw4[pos];
      uint2 u0 = *(const uint2*)(xp_tb + iv.x + c4);
      uint2 u1 = *(const uint2*)(xp_tb + iv.y + c4);
      uint2 u2 = *(const uint2*)(xp_tb + iv.z + c4);
      uint2 u3 = *(const uint2*)(xp_tb + iv.w + c4);
      float a0, a1, a2, a3;
      a0  = wq.x * __uint_as_float(u0.x << 16);
      a1  = wq.x * __uint_as_float(u0.x & 0xFFFF0000u);
      a2  = wq.x * __uint_as_float(u0.y << 16);
      a3  = wq.x * __uint_as_float(u0.y & 0xFFFF0000u);
      a0 = fmaf(wq.y, __uint_as_float(u1.x << 16), a0);
      a1 = fmaf(wq.y, __uint_as_float(u1.x & 0xFFFF0000u), a1);
      a2 = fmaf(wq.y, __uint_as_float(u1.y << 16), a2);
      a3 = fmaf(wq.y, __uint_as_float(u1.y & 0xFFFF0000u), a3);
      a0 = fmaf(wq.z, __uint_as_float(u2.x << 16), a0);
      a1 = fmaf(wq.z, __uint_as_float(u2.x & 0xFFFF0000u), a1);
      a2 = fmaf(wq.z, __uint_as_float(u2.y << 16), a2);
      a3 = fmaf(wq.z, __uint_as_float(u2.y & 0xFFFF0000u), a3);
      a0 = fmaf(wq.w, __uint_as_float(u3.x << 16), a0);
      a1 = fmaf(wq.w, __uint_as_float(u3.x & 0xFFFF0000u), a1);
      a2 = fmaf(wq.w, __uint_as_float(u3.y << 16), a2);
      a3 = fmaf(wq.w, __uint_as_float(u3.y & 0xFFFF0000u), a3);
      // pack 4 f32 -> 4 bf16 (truncate)
      uint2 r;
      r.x = (__float_as_uint(a0) >> 16) | (__float_as_uint(a1) & 0xFFFF0000u);
      r.y = (__float_as_uint(a2) >> 16) | (__float_as_uint(a3) & 0xFFFF0000u);
      u32 byte = (u32)pos * 512u + (u32)c4 * 2u;
      byte ^= (u32)(pos & 7) << 4;
      *(uint2*)((char*)samp + byte) = r;
    }
    __syncthreads();

    // GEMM: 8 K-chunks of 32 channels
#pragma unroll 1
    for (int cc = 0; cc < 8; cc++) {
      int c0 = cc * 32;
      bf16x8 bfr[4];
#pragma unroll
      for (int nt = 0; nt < 4; nt++) {
        int pos = nt * 16 + (lane & 15);
        u32 byte = (u32)pos * 512u + (u32)(c0 + (lane >> 4) * 8) * 2u;
        byte ^= (u32)(pos & 7) << 4;
        bfr[nt] = *(const bf16x8*)((const char*)samp + byte);
      }
      const u16* wp = wt_b + ((size_t)tap * 256 + wv * 128 + (lane & 15)) * 256
                      + c0 + (lane >> 4) * 8;
      bf16x8 afr[8];
#pragma unroll
      for (int mt = 0; mt < 8; mt++)
        afr[mt] = *(const bf16x8*)(wp + mt * 16 * 256);
#pragma unroll
      for (int mt = 0; mt < 8; mt++)
#pragma unroll
        for (int nt = 0; nt < 4; nt++)
          acc[mt][nt] = __builtin_amdgcn_mfma_f32_16x16x32_bf16(
              afr[mt], bfr[nt], acc[mt][nt], 0, 0, 0);
    }
  }

  // epilogue: D[oc][pos] -> d NCHW
#pragma unroll
  for (int mt = 0; mt < 8; mt++) {
    int oc = wv * 128 + mt * 16 + (lane >> 4) * 4;
#pragma unroll
    for (int nt = 0; nt < 4; nt++) {
      int P = P0 + nt * 16 + (lane & 15);
      int b = P / HW;
      int p = P - b * HW;
      float* dst = d + ((size_t)(b * CH + oc)) * HW + p;
#pragma unroll
      for (int r = 0; r < 4; r++)
        dst[(size_t)r * HW] = acc[mt][nt][r];
    }
  }
}

// ---------------------------------------------------------------------------
// K8: final = relu(d*sc + sh + xp), all NCHW, elementwise float4
// ---------------------------------------------------------------------------
__global__ __launch_bounds__(256) void final_nchw(
    const float* __restrict__ d, const float* __restrict__ xp,
    const float* __restrict__ st2, const float* __restrict__ ng,
    const float* __restrict__ nb, float* __restrict__ out)
{
  u32 i4 = blockIdx.x * 256 + threadIdx.x;
  u32 e = i4 * 4;                       // element index, < 7372800
  int row = (int)(e / HW);              // b*256 + c
  int c = row & 255;
  float m = st2[c], rs = st2[CH + c];
  float sc = ng[c] * rs;
  float sh = nb[c] - m * sc;
  float4 dv = *(const float4*)(d + e);
  float4 xv = *(const float4*)(xp + e);
  float4 o;
  o.x = dv.x * sc + sh + xv.x;
  o.y = dv.y * sc + sh + xv.y;
  o.z = dv.z * sc + sh + xv.z;
  o.w = dv.w * sc + sh + xv.w;
  o.x = o.x > 0.f ? o.x : 0.f;
  o.y = o.y > 0.f ? o.y : 0.f;
  o.z = o.z > 0.f ? o.z : 0.f;
  o.w = o.w > 0.f ? o.w : 0.f;
  *(float4*)(out + e) = o;
}

// ---------------------------------------------------------------------------
extern "C" void kernel_launch(void* const* d_in, const int* in_sizes, int n_in,
                              void* d_out, int out_size, void* d_ws, size_t ws_size,
                              hipStream_t stream)
{
  const float* x       = (const float*)d_in[0];
  const float* conv1_w = (const float*)d_in[1];
  const float* bn1_g   = (const float*)d_in[2];
  const float* bn1_b   = (const float*)d_in[3];
  const float* off_w   = (const float*)d_in[4];
  const float* off_b   = (const float*)d_in[5];
  const float* dcn_w   = (const float*)d_in[6];
  const float* norm_g  = (const float*)d_in[8];
  const float* norm_b  = (const float*)d_in[9];
  float* out = (float*)d_out;

  char* ws = (char*)d_ws;
  size_t o = 0;
  float* out1   = (float*)(ws + o); o += (size_t)PTOT * CH * 4;        // 29.5 MB (becomes xp NCHW)
  u16*   xp_tb  = (u16*)  (ws + o); o += (size_t)PTOT * CH * 2;        // 14.75 MB NHWC bf16
  float* offp   = (float*)(ws + o); o += (size_t)8 * BATCH * 27 * HW * 4; // 24.9 MB
  float* dbuf   = (float*)(ws + o); o += (size_t)PTOT * CH * 4;        // 29.5 MB NCHW
  u16*   wt_b   = (u16*)  (ws + o); o += (size_t)9 * 256 * 256 * 2;    // 1.18 MB
  float* wt_off = (float*)(ws + o); o += (size_t)512 * 9 * 27 * 4;     // 0.5 MB
  float4* wts4  = (float4*)(ws + o); o += (size_t)9 * PTOT * 16;       // 4.15 MB
  int4*   idx4  = (int4*) (ws + o); o += (size_t)9 * PTOT * 16;        // 4.15 MB
  float* st     = (float*)(ws + o); o += 512 * 4;
  float* st2    = (float*)(ws + o); o += 512 * 4;

  prep_wts<<<2304, 256, 0, stream>>>(dcn_w, off_w, wt_b, wt_off);
  conv1_gemm<<<dim3(57, 4, 8), 256, 0, stream>>>(x, conv1_w, out1);
  stats_nchw<<<256, 256, 0, stream>>>(out1, st);
  norm_transpose<<<dim3(113, 8, 8), 256, 0, stream>>>(out1, st, bn1_g, bn1_b, xp_tb);
  off_conv<<<dim3(15, 8, 8), 256, 0, stream>>>(x, out1, wt_off, offp);
  off_finalize<<<(9 * PTOT + 255) / 256, 256, 0, stream>>>(offp, off_b, wts4, idx4);
  deform_mfma<<<450, 128, 0, stream>>>(xp_tb, wts4, idx4, wt_b, dbuf);
  stats_nchw<<<256, 256, 0, stream>>>(dbuf, st2);
  final_nchw<<<7200, 256, 0, stream>>>(dbuf, out1, st2, norm_g, norm_b, out);
}

// Round 3
// 381.491 us; speedup vs baseline: 3.2503x; 1.3369x over previous
//
#include <hip/hip_runtime.h>
#include <math.h>

// Problem constants
#define BATCH 8
#define CH 256
#define HH 45
#define WW 80
#define HW 3600        // 45*80
#define PTOT 28800     // BATCH*HW

typedef unsigned short u16;
typedef unsigned int   u32;
typedef __attribute__((ext_vector_type(8))) short bf16x8;
typedef __attribute__((ext_vector_type(4))) float f32x4;

struct __align__(8) us4 { u16 x, y, z, w; };

__device__ __forceinline__ u16 bf16_rne(float x) {
  u32 u = __float_as_uint(x);
  u += 0x7FFF + ((u >> 16) & 1);
  return (u16)(u >> 16);
}

// ---------------------------------------------------------------------------
// K0: weight prep (all bf16 transposes)
//   w1b[o][c]            = conv1_w[o][c]
//   wt_offb[tap][oc][c]  = off_w[oc][c][tap]  (oc padded 27->32 with 0)
//   wt_b[tap][oc][c]     = dcn_w[oc][c][tap]
// ---------------------------------------------------------------------------
__global__ __launch_bounds__(256) void prep_wts(
    const float* __restrict__ conv1_w, const float* __restrict__ off_w,
    const float* __restrict__ dcn_w,
    u16* __restrict__ w1b, u16* __restrict__ wt_offb, u16* __restrict__ wt_b)
{
  int i = blockIdx.x * 256 + threadIdx.x;
  if (i < 256 * 256) {
    w1b[i] = bf16_rne(conv1_w[i]);
  }
  if (i < 9 * 32 * 512) {
    int tap = i >> 14;           // / 16384
    int r   = i & 16383;
    int oc  = r >> 9;
    int c   = r & 511;
    float v = (oc < 27) ? off_w[((size_t)oc * 512 + c) * 9 + tap] : 0.f;
    wt_offb[i] = bf16_rne(v);
  }
  if (i < 9 * 256 * 256) {
    int c = i & 255;
    int oc = (i >> 8) & 255;
    int tap = i >> 16;
    wt_b[i] = bf16_rne(dcn_w[((size_t)oc * 256 + c) * 9 + tap]);
  }
}

// ---------------------------------------------------------------------------
// K1: flip-transpose x -> concat[P][0:256] bf16 (w-flipped NHWC)
// concat[(b,h,w')][c] = x[b][c][h][79-w']
// ---------------------------------------------------------------------------
__global__ __launch_bounds__(256) void flip_transpose(
    const float* __restrict__ x, u16* __restrict__ concat)
{
  __shared__ float tile[32][36];
  const int b  = blockIdx.z;
  const int c0 = blockIdx.y * 32;
  const int p0 = blockIdx.x * 32;
  int rem = HW - p0; if (rem > 32) rem = 32;
  const int t = threadIdx.x;
  {
    int c = t >> 3, p4 = (t & 7) * 4;
    if (p4 < rem) {
      float4 v = *(const float4*)(x + ((size_t)b * CH + c0 + c) * HW + p0 + p4);
      *(float4*)&tile[c][p4] = v;
    }
  }
  __syncthreads();
  {
    int r = t >> 3, cq = (t & 7) * 4;
    if (r < rem) {
      int p = p0 + r;
      int h = p / WW, w = p - h * WW;
      int pf = h * WW + (WW - 1 - w);
      us4 o;
      o.x = bf16_rne(tile[cq + 0][r]);
      o.y = bf16_rne(tile[cq + 1][r]);
      o.z = bf16_rne(tile[cq + 2][r]);
      o.w = bf16_rne(tile[cq + 3][r]);
      *(us4*)(concat + ((size_t)b * HW + pf) * 512 + c0 + cq) = o;
    }
  }
}

// ---------------------------------------------------------------------------
// K2: conv1 via MFMA: out1[oc][P] = sum_c concat[Pflip][c] * w1b[oc][c]
// Block 256 thr (4 waves): 128 oc x 128 pos tile; wave = 64 oc x 64 pos.
// ---------------------------------------------------------------------------
__global__ __launch_bounds__(256) void conv1_mfma(
    const u16* __restrict__ concat, const u16* __restrict__ w1b,
    float* __restrict__ out1)
{
  const int t = threadIdx.x;
  const int wv = t >> 6, lane = t & 63;
  const int lr = lane & 15, lk = lane >> 4;
  const int oc0 = blockIdx.y * 128 + (wv & 1) * 64;
  const int P0  = blockIdx.x * 128 + (wv >> 1) * 64;

  const u16* bptr[4];
#pragma unroll
  for (int nt = 0; nt < 4; nt++) {
    int P = P0 + nt * 16 + lr;
    int b = P / HW, p = P - b * HW;
    int h = p / WW, w = p - h * WW;
    int pf = b * HW + h * WW + (WW - 1 - w);
    bptr[nt] = concat + (size_t)pf * 512 + lk * 8;
  }
  const u16* aptr = w1b + ((size_t)(oc0 + lr)) * 256 + lk * 8;

  f32x4 acc[4][4];
#pragma unroll
  for (int mt = 0; mt < 4; mt++)
#pragma unroll
    for (int nt = 0; nt < 4; nt++) acc[mt][nt] = (f32x4)0.f;

#pragma unroll
  for (int cc = 0; cc < 8; cc++) {
    bf16x8 af[4], bfv[4];
#pragma unroll
    for (int mt = 0; mt < 4; mt++)
      af[mt] = *(const bf16x8*)(aptr + (size_t)mt * 16 * 256 + cc * 32);
#pragma unroll
    for (int nt = 0; nt < 4; nt++)
      bfv[nt] = *(const bf16x8*)(bptr[nt] + cc * 32);
#pragma unroll
    for (int mt = 0; mt < 4; mt++)
#pragma unroll
      for (int nt = 0; nt < 4; nt++)
        acc[mt][nt] = __builtin_amdgcn_mfma_f32_16x16x32_bf16(
            af[mt], bfv[nt], acc[mt][nt], 0, 0, 0);
  }

#pragma unroll
  for (int mt = 0; mt < 4; mt++) {
    int oc = oc0 + mt * 16 + lk * 4;
#pragma unroll
    for (int nt = 0; nt < 4; nt++) {
      int P = P0 + nt * 16 + lr;
      int b = P / HW, p = P - b * HW;
      float* dst = out1 + ((size_t)(b * CH + oc)) * HW + p;
#pragma unroll
      for (int r = 0; r < 4; r++)
        dst[(size_t)r * HW] = acc[mt][nt][r];
    }
  }
}

// ---------------------------------------------------------------------------
// K3: per-channel mean/rstd over NCHW
// ---------------------------------------------------------------------------
__global__ __launch_bounds__(256) void stats_nchw(
    const float* __restrict__ src, float* __restrict__ st)
{
  const int c = blockIdx.x;
  const int t = threadIdx.x;
  float s = 0.f, s2 = 0.f;
  for (int b = 0; b < BATCH; b++) {
    const float* p = src + ((size_t)b * CH + c) * HW;
    for (int i = t; i < HW; i += 256) {
      float v = p[i];
      s += v; s2 += v * v;
    }
  }
  __shared__ float ls[256], ls2[256];
  ls[t] = s; ls2[t] = s2;
  __syncthreads();
  for (int off = 128; off > 0; off >>= 1) {
    if (t < off) { ls[t] += ls[t + off]; ls2[t] += ls2[t + off]; }
    __syncthreads();
  }
  if (t == 0) {
    float m = ls[0] / (float)PTOT;
    float var = ls2[0] / (float)PTOT - m * m;
    st[c] = m;
    st[CH + c] = rsqrtf(var + 1e-5f);
  }
}

// ---------------------------------------------------------------------------
// K4: normalize out1 in place (-> xp NCHW f32) and write concat[P][256:512] bf16
// ---------------------------------------------------------------------------
__global__ __launch_bounds__(256) void norm_transpose(
    float* __restrict__ out1, const float* __restrict__ st,
    const float* __restrict__ g, const float* __restrict__ bb,
    u16* __restrict__ concat)
{
  __shared__ float tile[32][36];   // [c][p]
  const int b  = blockIdx.z;
  const int c0 = blockIdx.y * 32;
  const int p0 = blockIdx.x * 32;
  int rem = HW - p0; if (rem > 32) rem = 32;
  const int t = threadIdx.x;

  {
    int c  = t >> 3;
    int p4 = (t & 7) * 4;
    int cg = c0 + c;
    float m  = st[cg], rs = st[CH + cg];
    float sc = g[cg] * rs;
    float sh = bb[cg] - m * sc;
    if (p4 < rem) {
      size_t base = ((size_t)b * CH + cg) * HW + p0;
      float4 v = *(const float4*)(out1 + base + p4);
      v.x = v.x * sc + sh; v.y = v.y * sc + sh;
      v.z = v.z * sc + sh; v.w = v.w * sc + sh;
      *(float4*)(out1 + base + p4) = v;
      *(float4*)&tile[c][p4] = v;
    }
  }
  __syncthreads();
  {
    int r  = t >> 3;
    int cq = (t & 7) * 4;
    if (r < rem) {
      us4 o;
      o.x = bf16_rne(tile[cq + 0][r]);
      o.y = bf16_rne(tile[cq + 1][r]);
      o.z = bf16_rne(tile[cq + 2][r]);
      o.w = bf16_rne(tile[cq + 3][r]);
      *(us4*)(concat + ((size_t)b * HW + p0 + r) * 512 + 256 + c0 + cq) = o;
    }
  }
}

// ---------------------------------------------------------------------------
// K5: offset conv via MFMA: off[oc 32][P] over concat (K = 9 taps x 512 ch).
// Block 128 thr (2 waves); each wave 16 positions, all 32 oc.
// B-frags read shifted NHWC rows directly from global; OOB -> zero frag.
// ---------------------------------------------------------------------------
__global__ __launch_bounds__(128) void off_mfma(
    const u16* __restrict__ concat, const u16* __restrict__ wt_offb,
    float* __restrict__ offout)
{
  const int t = threadIdx.x;
  const int wv = t >> 6, lane = t & 63;
  const int lr = lane & 15, lk = lane >> 4;
  const int P = blockIdx.x * 32 + wv * 16 + lr;
  const int b = P / HW, p = P - b * HW;
  const int h = p / WW, w = p - h * WW;

  f32x4 acc[2];
  acc[0] = (f32x4)0.f; acc[1] = (f32x4)0.f;

#pragma unroll 1
  for (int tap = 0; tap < 9; tap++) {
    int dy = tap / 3 - 1, dx = tap % 3 - 1;
    bool valid = ((unsigned)(h + dy) < HH) && ((unsigned)(w + dx) < WW);
    int Ps = valid ? (P + dy * WW + dx) : P;
    const u16* bp = concat + (size_t)Ps * 512 + lk * 8;
    const u16* ap = wt_offb + ((size_t)tap * 32 + lr) * 512 + lk * 8;
#pragma unroll
    for (int cc = 0; cc < 16; cc++) {
      bf16x8 bfv = *(const bf16x8*)(bp + cc * 32);
      if (!valid) bfv = (bf16x8)(short)0;
      bf16x8 af0 = *(const bf16x8*)(ap + cc * 32);
      bf16x8 af1 = *(const bf16x8*)(ap + 16 * 512 + cc * 32);
      acc[0] = __builtin_amdgcn_mfma_f32_16x16x32_bf16(af0, bfv, acc[0], 0, 0, 0);
      acc[1] = __builtin_amdgcn_mfma_f32_16x16x32_bf16(af1, bfv, acc[1], 0, 0, 0);
    }
  }

#pragma unroll
  for (int mt = 0; mt < 2; mt++) {
    int oc = mt * 16 + lk * 4;
#pragma unroll
    for (int r = 0; r < 4; r++)
      offout[(size_t)(oc + r) * PTOT + P] = acc[mt][r];
  }
}

// ---------------------------------------------------------------------------
// K6: finalize offsets -> bilinear params per (tap, P).
// ---------------------------------------------------------------------------
__global__ __launch_bounds__(256) void off_finalize(
    const float* __restrict__ offout, const float* __restrict__ off_b,
    float4* __restrict__ wts4, int4* __restrict__ idx4)
{
  int i = blockIdx.x * 256 + threadIdx.x;
  if (i >= 9 * PTOT) return;
  int k = i / PTOT;
  int P = i - k * PTOT;
  int b = P / HW;
  int p = P - b * HW;
  int h = p / WW;
  int w = p - h * WW;

  float dy = off_b[2 * k]     + offout[(size_t)(2 * k    ) * PTOT + P];
  float dx = off_b[2 * k + 1] + offout[(size_t)(2 * k + 1) * PTOT + P];
  float ml = off_b[18 + k]    + offout[(size_t)(18 + k   ) * PTOT + P];

  float m = 1.f / (1.f + expf(-ml));
  float ph = dy + (float)(k / 3 - 1) + (float)h;
  float pw = dx + (float)(k % 3 - 1) + (float)w;
  float h0f = floorf(ph), w0f = floorf(pw);
  float lh = ph - h0f, lw = pw - w0f;
  int h0 = (int)h0f, w0 = (int)w0f;
  int h1 = h0 + 1, w1 = w0 + 1;
  float vh0 = (h0 >= 0 && h0 < HH) ? 1.f : 0.f;
  float vh1 = (h1 >= 0 && h1 < HH) ? 1.f : 0.f;
  float vw0 = (w0 >= 0 && w0 < WW) ? 1.f : 0.f;
  float vw1 = (w1 >= 0 && w1 < WW) ? 1.f : 0.f;
  float4 wv;
  wv.x = (1.f - lh) * (1.f - lw) * m * vh0 * vw0;
  wv.y = (1.f - lh) * lw         * m * vh0 * vw1;
  wv.z = lh * (1.f - lw)         * m * vh1 * vw0;
  wv.w = lh * lw                 * m * vh1 * vw1;
  int hc0 = min(max(h0, 0), HH - 1), hc1 = min(max(h1, 0), HH - 1);
  int wc0 = min(max(w0, 0), WW - 1), wc1 = min(max(w1, 0), WW - 1);
  int base = b * HW;
  int4 iv;
  iv.x = (base + hc0 * WW + wc0) * 512 + 256;
  iv.y = (base + hc0 * WW + wc1) * 512 + 256;
  iv.z = (base + hc1 * WW + wc0) * 512 + 256;
  iv.w = (base + hc1 * WW + wc1) * 512 + 256;
  wts4[i] = wv;
  idx4[i] = iv;
}

// ---------------------------------------------------------------------------
// K7: deformable conv via MFMA bf16 (xp region of concat, stride 512).
// ---------------------------------------------------------------------------
__global__ __launch_bounds__(128) void deform_mfma(
    const u16* __restrict__ concat,
    const float4* __restrict__ wts4, const int4* __restrict__ idx4,
    const u16* __restrict__ wt_b,
    float* __restrict__ d)
{
  __shared__ u16   samp[64 * 256];   // swizzled: byte ^= (pos&7)<<4
  __shared__ float4 sw4[64];
  __shared__ int4   sidx4[64];

  const int t    = threadIdx.x;
  const int wv   = t >> 6;
  const int lane = t & 63;
  const int P0   = blockIdx.x * 64;

  f32x4 acc[8][4];
#pragma unroll
  for (int mt = 0; mt < 8; mt++)
#pragma unroll
    for (int nt = 0; nt < 4; nt++) acc[mt][nt] = (f32x4)0.f;

  const int c4 = lane * 4;

  for (int tap = 0; tap < 9; tap++) {
    __syncthreads();
    if (t < 64) {
      sw4[t]   = wts4[(size_t)tap * PTOT + P0 + t];
      sidx4[t] = idx4[(size_t)tap * PTOT + P0 + t];
    }
    __syncthreads();

#pragma unroll 2
    for (int it = 0; it < 32; it++) {
      int pos = it * 2 + wv;
      int4  iv = sidx4[pos];
      float4 wq = sw4[pos];
      uint2 u0 = *(const uint2*)(concat + iv.x + c4);
      uint2 u1 = *(const uint2*)(concat + iv.y + c4);
      uint2 u2 = *(const uint2*)(concat + iv.z + c4);
      uint2 u3 = *(const uint2*)(concat + iv.w + c4);
      float a0, a1, a2, a3;
      a0  = wq.x * __uint_as_float(u0.x << 16);
      a1  = wq.x * __uint_as_float(u0.x & 0xFFFF0000u);
      a2  = wq.x * __uint_as_float(u0.y << 16);
      a3  = wq.x * __uint_as_float(u0.y & 0xFFFF0000u);
      a0 = fmaf(wq.y, __uint_as_float(u1.x << 16), a0);
      a1 = fmaf(wq.y, __uint_as_float(u1.x & 0xFFFF0000u), a1);
      a2 = fmaf(wq.y, __uint_as_float(u1.y << 16), a2);
      a3 = fmaf(wq.y, __uint_as_float(u1.y & 0xFFFF0000u), a3);
      a0 = fmaf(wq.z, __uint_as_float(u2.x << 16), a0);
      a1 = fmaf(wq.z, __uint_as_float(u2.x & 0xFFFF0000u), a1);
      a2 = fmaf(wq.z, __uint_as_float(u2.y << 16), a2);
      a3 = fmaf(wq.z, __uint_as_float(u2.y & 0xFFFF0000u), a3);
      a0 = fmaf(wq.w, __uint_as_float(u3.x << 16), a0);
      a1 = fmaf(wq.w, __uint_as_float(u3.x & 0xFFFF0000u), a1);
      a2 = fmaf(wq.w, __uint_as_float(u3.y << 16), a2);
      a3 = fmaf(wq.w, __uint_as_float(u3.y & 0xFFFF0000u), a3);
      uint2 r;
      r.x = (__float_as_uint(a0) >> 16) | (__float_as_uint(a1) & 0xFFFF0000u);
      r.y = (__float_as_uint(a2) >> 16) | (__float_as_uint(a3) & 0xFFFF0000u);
      u32 byte = (u32)pos * 512u + (u32)c4 * 2u;
      byte ^= (u32)(pos & 7) << 4;
      *(uint2*)((char*)samp + byte) = r;
    }
    __syncthreads();

#pragma unroll 1
    for (int cc = 0; cc < 8; cc++) {
      int c0 = cc * 32;
      bf16x8 bfr[4];
#pragma unroll
      for (int nt = 0; nt < 4; nt++) {
        int pos = nt * 16 + (lane & 15);
        u32 byte = (u32)pos * 512u + (u32)(c0 + (lane >> 4) * 8) * 2u;
        byte ^= (u32)(pos & 7) << 4;
        bfr[nt] = *(const bf16x8*)((const char*)samp + byte);
      }
      const u16* wp = wt_b + ((size_t)tap * 256 + wv * 128 + (lane & 15)) * 256
                      + c0 + (lane >> 4) * 8;
      bf16x8 afr[8];
#pragma unroll
      for (int mt = 0; mt < 8; mt++)
        afr[mt] = *(const bf16x8*)(wp + (size_t)mt * 16 * 256);
#pragma unroll
      for (int mt = 0; mt < 8; mt++)
#pragma unroll
        for (int nt = 0; nt < 4; nt++)
          acc[mt][nt] = __builtin_amdgcn_mfma_f32_16x16x32_bf16(
              afr[mt], bfr[nt], acc[mt][nt], 0, 0, 0);
    }
  }

#pragma unroll
  for (int mt = 0; mt < 8; mt++) {
    int oc = wv * 128 + mt * 16 + (lane >> 4) * 4;
#pragma unroll
    for (int nt = 0; nt < 4; nt++) {
      int P = P0 + nt * 16 + (lane & 15);
      int b = P / HW;
      int p = P - b * HW;
      float* dst = d + ((size_t)(b * CH + oc)) * HW + p;
#pragma unroll
      for (int r = 0; r < 4; r++)
        dst[(size_t)r * HW] = acc[mt][nt][r];
    }
  }
}

// ---------------------------------------------------------------------------
// K8: final = relu(d*sc + sh + xp), all NCHW, elementwise float4
// ---------------------------------------------------------------------------
__global__ __launch_bounds__(256) void final_nchw(
    const float* __restrict__ d, const float* __restrict__ xp,
    const float* __restrict__ st2, const float* __restrict__ ng,
    const float* __restrict__ nb, float* __restrict__ out)
{
  u32 i4 = blockIdx.x * 256 + threadIdx.x;
  u32 e = i4 * 4;
  int row = (int)(e / HW);
  int c = row & 255;
  float m = st2[c], rs = st2[CH + c];
  float sc = ng[c] * rs;
  float sh = nb[c] - m * sc;
  float4 dv = *(const float4*)(d + e);
  float4 xv = *(const float4*)(xp + e);
  float4 o;
  o.x = dv.x * sc + sh + xv.x;
  o.y = dv.y * sc + sh + xv.y;
  o.z = dv.z * sc + sh + xv.z;
  o.w = dv.w * sc + sh + xv.w;
  o.x = o.x > 0.f ? o.x : 0.f;
  o.y = o.y > 0.f ? o.y : 0.f;
  o.z = o.z > 0.f ? o.z : 0.f;
  o.w = o.w > 0.f ? o.w : 0.f;
  *(float4*)(out + e) = o;
}

// ---------------------------------------------------------------------------
extern "C" void kernel_launch(void* const* d_in, const int* in_sizes, int n_in,
                              void* d_out, int out_size, void* d_ws, size_t ws_size,
                              hipStream_t stream)
{
  const float* x       = (const float*)d_in[0];
  const float* conv1_w = (const float*)d_in[1];
  const float* bn1_g   = (const float*)d_in[2];
  const float* bn1_b   = (const float*)d_in[3];
  const float* off_w   = (const float*)d_in[4];
  const float* off_b   = (const float*)d_in[5];
  const float* dcn_w   = (const float*)d_in[6];
  const float* norm_g  = (const float*)d_in[8];
  const float* norm_b  = (const float*)d_in[9];
  float* out = (float*)d_out;

  char* ws = (char*)d_ws;
  size_t o = 0;
  float* out1    = (float*)(ws + o); o += (size_t)PTOT * CH * 4;       // 29.5 MB (becomes xp NCHW)
  u16*   concat  = (u16*)  (ws + o); o += (size_t)PTOT * 512 * 2;      // 29.5 MB NHWC bf16 [flipx | xp]
  float* dbuf    = (float*)(ws + o); o += (size_t)PTOT * CH * 4;       // 29.5 MB NCHW
  float* offout  = (float*)(ws + o); o += (size_t)32 * PTOT * 4;       // 3.7 MB
  u16*   wt_b    = (u16*)  (ws + o); o += (size_t)9 * 256 * 256 * 2;   // 1.18 MB
  u16*   wt_offb = (u16*)  (ws + o); o += (size_t)9 * 32 * 512 * 2;    // 0.29 MB
  u16*   w1b     = (u16*)  (ws + o); o += (size_t)256 * 256 * 2;       // 0.13 MB
  float4* wts4   = (float4*)(ws + o); o += (size_t)9 * PTOT * 16;      // 4.15 MB
  int4*   idx4   = (int4*) (ws + o); o += (size_t)9 * PTOT * 16;       // 4.15 MB
  float* st      = (float*)(ws + o); o += 512 * 4;
  float* st2     = (float*)(ws + o); o += 512 * 4;

  prep_wts<<<2304, 256, 0, stream>>>(conv1_w, off_w, dcn_w, w1b, wt_offb, wt_b);
  flip_transpose<<<dim3(113, 8, 8), 256, 0, stream>>>(x, concat);
  conv1_mfma<<<dim3(225, 2), 256, 0, stream>>>(concat, w1b, out1);
  stats_nchw<<<256, 256, 0, stream>>>(out1, st);
  norm_transpose<<<dim3(113, 8, 8), 256, 0, stream>>>(out1, st, bn1_g, bn1_b, concat);
  off_mfma<<<900, 128, 0, stream>>>(concat, wt_offb, offout);
  off_finalize<<<(9 * PTOT + 255) / 256, 256, 0, stream>>>(offout, off_b, wts4, idx4);
  deform_mfma<<<450, 128, 0, stream>>>(concat, wts4, idx4, wt_b, dbuf);
  stats_nchw<<<256, 256, 0, stream>>>(dbuf, st2);
  final_nchw<<<7200, 256, 0, stream>>>(dbuf, out1, st2, norm_g, norm_b, out);
}